// Round 1
// 376.031 us; speedup vs baseline: 1.0647x; 1.0647x over previous
//
#include <hip/hip_runtime.h>
#include <hip/hip_bf16.h>

// All external tensors are FLOAT32; bf16 is used only internally for MFMA.
typedef __bf16 bf16;
typedef __bf16 bfrag __attribute__((ext_vector_type(8)));   // 8 bf16 = 4 VGPRs (MFMA A/B)
typedef __bf16 bf16x4 __attribute__((ext_vector_type(4)));  // packed 8B P-write
typedef float f32x4 __attribute__((ext_vector_type(4)));    // MFMA C/D

constexpr int Bc = 4, Sc = 2048, Hc = 16, ADc = 64, HIDc = 1024;
constexpr size_t QKV_ELEMS = (size_t)Bc * Hc * Sc * ADc;    // 8388608 (16 MB bf16)

__device__ __forceinline__ void gload_lds16(const void* g, void* lds) {
  __builtin_amdgcn_global_load_lds(
      (const __attribute__((address_space(1))) unsigned int*)g,
      (__attribute__((address_space(3))) unsigned int*)lds, 16, 0, 0);
}

__device__ __forceinline__ bfrag ldb(const bf16* p) {
  return *(const bfrag*)p;
}

// ---------------------------------------------------------------------------
// fp32 -> bf16 conversion, 8 elements/thread.
// ---------------------------------------------------------------------------
__global__ __launch_bounds__(256) void f2b(const float* __restrict__ s,
                                           bf16* __restrict__ d) {
  const size_t i = ((size_t)blockIdx.x * 256 + threadIdx.x) * 8;
  const float4 a = *(const float4*)(s + i);
  const float4 b = *(const float4*)(s + i + 4);
  bfrag o = {(bf16)a.x, (bf16)a.y, (bf16)a.z, (bf16)a.w,
             (bf16)b.x, (bf16)b.y, (bf16)b.z, (bf16)b.w};
  *(bfrag*)(d + i) = o;
}

// ---------------------------------------------------------------------------
// GEMM C = A * B^T  (A:[M][K], Bm:[N][K], bf16 in, fp32 accum)
// MODE 0: A row-major; epilogue scatters bf16 Q(x0.125)/K/Vt(transposed)
// MODE 1: A in head-split layout [b][h][s][64]; fp32 store to Cf[M][Ndim]
// ---------------------------------------------------------------------------
template <int MODE>
__global__ __launch_bounds__(256) void gemm_bt(
    const bf16* __restrict__ A,
    const bf16* __restrict__ Bm,
    bf16* __restrict__ C0,
    bf16* __restrict__ C1,
    bf16* __restrict__ C2,
    float* __restrict__ Cf,
    int Kdim, int Ndim)
{
  __shared__ __align__(16) bf16 As[128 * 32];
  __shared__ __align__(16) bf16 Bs[128 * 32];

  const int tid  = threadIdx.x;
  const int wave = tid >> 6;
  const int lane = tid & 63;
  const int n16  = lane & 15;
  const int quad = lane >> 4;
  const int wm   = wave & 1;
  const int wn   = wave >> 1;
  const int m0   = blockIdx.y * 128;
  const int n0   = blockIdx.x * 128;

  const f32x4 fzero = {0.f, 0.f, 0.f, 0.f};
  f32x4 acc[4][4];
#pragma unroll
  for (int i = 0; i < 4; ++i)
#pragma unroll
    for (int j = 0; j < 4; ++j) acc[i][j] = fzero;

  const int lcol = (lane & 3) * 8;  // element offset within the 32-elem LDS row

  for (int k0 = 0; k0 < Kdim; k0 += 32) {
#pragma unroll
    for (int c = 0; c < 2; ++c) {
      const int chunk = wave * 2 + c;          // 0..7, 16 rows each
      const int row   = chunk * 16 + (lane >> 2);
      const bf16* agp;
      if (MODE == 0) {
        agp = A + (size_t)(m0 + row) * Kdim + k0 + lcol;
      } else {
        // A = O in head-split layout [b][h][s][64]; head h = k0>>6.
        const int gs = m0 + row;               // global row (b*2048 + s)
        const int h  = k0 >> 6;
        agp = A + (((size_t)(gs >> 11) * Hc + h) * Sc + (gs & 2047)) * ADc
                + (k0 & 63) + lcol;
      }
      gload_lds16(agp, (char*)As + chunk * 1024);
      gload_lds16(Bm + (size_t)(n0 + row) * Kdim + k0 + lcol,
                  (char*)Bs + chunk * 1024);
    }
    __syncthreads();

    bfrag af[4], bf[4];
#pragma unroll
    for (int i = 0; i < 4; ++i)
      af[i] = ldb(As + (wm * 64 + i * 16 + n16) * 32 + quad * 8);
#pragma unroll
    for (int j = 0; j < 4; ++j)
      bf[j] = ldb(Bs + (wn * 64 + j * 16 + n16) * 32 + quad * 8);
#pragma unroll
    for (int i = 0; i < 4; ++i)
#pragma unroll
      for (int j = 0; j < 4; ++j)
        acc[i][j] = __builtin_amdgcn_mfma_f32_16x16x32_bf16(af[i], bf[j], acc[i][j], 0, 0, 0);
    __syncthreads();
  }

#pragma unroll
  for (int i = 0; i < 4; ++i) {
    const int grow = m0 + wm * 64 + i * 16 + quad * 4;
#pragma unroll
    for (int j = 0; j < 4; ++j) {
      const int col_local = wn * 64 + j * 16 + n16;
#pragma unroll
      for (int r = 0; r < 4; ++r) {
        const int row = grow + r;
        const float v = acc[i][j][r];
        if (MODE == 1) {
          Cf[(size_t)row * Ndim + n0 + col_local] = v;   // fp32 final output
        } else {
          const int seg = n0 >> 10;               // 0=Q 1=K 2=V (uniform per block)
          const int hid = (n0 & 1023) + col_local;
          const int h = hid >> 6, a = hid & 63;
          const int bi = row >> 11, s = row & 2047;
          if (seg == 0)       // Q pre-scaled by 1/sqrt(64) (power of 2: exact)
            C0[(((size_t)bi * Hc + h) * Sc + s) * ADc + a] = (bf16)(v * 0.125f);
          else if (seg == 1)
            C1[(((size_t)bi * Hc + h) * Sc + s) * ADc + a] = (bf16)v;
          else                // V stored transposed: Vt[bh][a][s]
            C2[(((size_t)bi * Hc + h) * ADc + a) * Sc + s] = (bf16)v;
        }
      }
    }
  }
}

// ---------------------------------------------------------------------------
// Pack int32 mask -> 1 bit per element.
// ---------------------------------------------------------------------------
__global__ __launch_bounds__(256) void mask_pack(const int* __restrict__ mask,
                                                 unsigned* __restrict__ bits) {
  const int w = blockIdx.x * 256 + threadIdx.x;
  const int4* p = (const int4*)(mask + (size_t)w * 32);
  unsigned out = 0;
#pragma unroll
  for (int i = 0; i < 8; ++i) {
    int4 m = p[i];
    out |= (unsigned)(m.x != 0) << (i * 4);
    out |= (unsigned)(m.y != 0) << (i * 4 + 1);
    out |= (unsigned)(m.z != 0) << (i * 4 + 2);
    out |= (unsigned)(m.w != 0) << (i * 4 + 3);
  }
  bits[w] = out;
}

// ---------------------------------------------------------------------------
// Flash attention, flat softmax, BLOCK-staged K/V (round-8: swapped QK^T).
// 512 threads = 8 waves; block owns 128 q-rows of one bh. Per 64-key tile,
// K (64x64) and V^T (64x64) are staged once into XOR-swizzled LDS
// (elem ^= (row&7)*8 -> frag reads hit bank group 4*(quad^(n16&7)): uniform
// 8-lane spread, conflict-free sweep). QK^T is computed SWAPPED:
// S^T = mfma(K, Q), so each lane holds one query's P-row (query = n16) with
// CONSECUTIVE keys along the accumulator (k = 16*nt + 4*quad + r). This makes
// P packable: 4x 8-byte ds_write_b64 of bf16x4 (vs 16 scalar u16 writes with
// 4-8-way bank conflicts) and one uint2 mask load per tile (vs 4). The
// softmax denominator is a single scalar register per lane (its query),
// reduced across quads only in the epilogue. PV step unchanged:
// O = mfma(P, Vt) from per-wave private P in LDS.
// ---------------------------------------------------------------------------
__global__ __launch_bounds__(512) void attn(
    const bf16* __restrict__ Qw,
    const bf16* __restrict__ Kw,
    const bf16* __restrict__ Vtw,
    const unsigned* __restrict__ mbits,
    bf16* __restrict__ Ow)   // == Qw (aliased)
{
  __shared__ __align__(16) bf16 Ks[64 * 64];        // [key][dim], XOR-swizzled
  __shared__ __align__(16) bf16 Vs[64 * 64];        // [dim][key], XOR-swizzled
  __shared__ __align__(16) bf16 Plds[8][16][72];    // per-wave P[query][key]

  const int tid  = threadIdx.x;
  const int wave = tid >> 6, lane = tid & 63;
  const int n16  = lane & 15, quad = lane >> 4;
  const int q4   = quad * 4;
  const int bh   = blockIdx.x >> 4, qb = blockIdx.x & 15;
  const int b    = bh >> 4;
  const int q0   = qb * 128 + wave * 16;

  // staging coords: thread t -> row t/8, 8-elem chunk (t%8)*8; swizzled dest
  const int srow = tid >> 3;
  const int scol = (tid & 7) * 8;
  const bf16* gK = Kw  + ((size_t)bh * Sc + srow) * ADc + scol;  // +k0*ADc per tile
  const bf16* gV = Vtw + ((size_t)bh * ADc + srow) * Sc + scol;  // +k0 per tile
  bf16* lK = Ks + srow * 64 + (scol ^ ((srow & 7) * 8));
  bf16* lV = Vs + srow * 64 + (scol ^ ((srow & 7) * 8));

  // frag-read swizzled element offsets (row&7 == n16&7 for rows nt*16+n16)
  const int fsw  = (n16 & 7) * 8;
  const int off0 = (quad * 8) ^ fsw;
  const int off1 = (32 + quad * 8) ^ fsw;

  // Q A/B-frags, resident all kernel (pre-scaled by 0.125 in gemm epilogue)
  const bf16* qrow = Qw + ((size_t)bh * Sc + q0 + n16) * ADc;
  const bfrag qf0 = ldb(qrow + quad * 8);
  const bfrag qf1 = ldb(qrow + 32 + quad * 8);

  const f32x4 fzero = {0.f, 0.f, 0.f, 0.f};
  float li = 0.f;                 // denominator for query n16 (lane-local)
  f32x4 of[4];
#pragma unroll
  for (int nt = 0; nt < 4; ++nt) of[nt] = fzero;

  // one mask row per lane: its query q0+n16; 64 key-bits per tile = uint2
  const unsigned* mq = mbits + ((size_t)b * Sc + q0 + n16) * (Sc / 32);

  // stage tile 0
  {
    bfrag k0r = ldb(gK);
    bfrag v0r = ldb(gV);
    *(bfrag*)lK = k0r;
    *(bfrag*)lV = v0r;
  }
  __syncthreads();

  for (int kt = 0; kt < Sc / 64; ++kt) {
    // prefetch tile kt+1 into regs (wraps on last iter: harmless)
    const int kn0 = ((kt + 1) & 31) * 64;
    const bfrag kpre = ldb(gK + (size_t)kn0 * ADc);
    const bfrag vpre = ldb(gV + kn0);

    // mask bits early (latency overlapped with QK^T)
    const uint2 mwv = *(const uint2*)(mq + kt * 2);

    // S^T = K Q^T from LDS K-frags (A = K rows, B = Q rows)
    // lane holds: query = n16, keys = 16*nt + 4*quad + r
    f32x4 sf[4];
#pragma unroll
    for (int nt = 0; nt < 4; ++nt) {
      const bf16* kr = Ks + (nt * 16 + n16) * 64;
      const bfrag kf0 = ldb(kr + off0);
      const bfrag kf1 = ldb(kr + off1);
      f32x4 c = fzero;
      c = __builtin_amdgcn_mfma_f32_16x16x32_bf16(kf0, qf0, c, 0, 0, 0);
      c = __builtin_amdgcn_mfma_f32_16x16x32_bf16(kf1, qf1, c, 0, 0, 0);
      sf[nt] = c;
    }

    // exp + mask + denominator + packed P write (4x 8B instead of 16x 2B)
    bf16* pl = &Plds[wave][0][0];
    __asm__ volatile("" ::: "memory");
#pragma unroll
    for (int nt = 0; nt < 4; ++nt) {
      const unsigned word = (nt & 2) ? mwv.y : mwv.x;
      bf16x4 t;
#pragma unroll
      for (int r = 0; r < 4; ++r) {
        float p = __expf(sf[nt][r]);
        if ((word >> ((nt & 1) * 16 + q4 + r)) & 1u) p = 0.f;
        li += p;
        t[r] = (bf16)p;
      }
      *(bf16x4*)(pl + n16 * 72 + nt * 16 + q4) = t;
    }
    __asm__ volatile("" ::: "memory");
    const bfrag pf0 = ldb(pl + n16 * 72 + quad * 8);
    const bfrag pf1 = ldb(pl + n16 * 72 + 32 + quad * 8);

    // O += P * V from LDS V-frags
#pragma unroll
    for (int nt = 0; nt < 4; ++nt) {
      const bf16* vr = Vs + (nt * 16 + n16) * 64;
      const bfrag vf0 = ldb(vr + off0);
      const bfrag vf1 = ldb(vr + off1);
      of[nt] = __builtin_amdgcn_mfma_f32_16x16x32_bf16(pf0, vf0, of[nt], 0, 0, 0);
      of[nt] = __builtin_amdgcn_mfma_f32_16x16x32_bf16(pf1, vf1, of[nt], 0, 0, 0);
    }

    // swap in the prefetched tile
    __syncthreads();
    *(bfrag*)lK = kpre;
    *(bfrag*)lV = vpre;
    __syncthreads();
  }

  // epilogue: reduce li across the 4 quads (lane-local query n16),
  // fetch the right denominator per output row, normalize, store.
  float s = li;
  s += __shfl_xor(s, 16);
  s += __shfl_xor(s, 32);
  const float inv = 1.f / s;
#pragma unroll
  for (int r = 0; r < 4; ++r) {
    const float invr = __shfl(inv, q4 + r, 64);   // denom of query q4+r
    const int q = q0 + q4 + r;
    bf16* orow = Ow + ((size_t)bh * Sc + q) * ADc;
#pragma unroll
    for (int nt = 0; nt < 4; ++nt)
      orow[nt * 16 + n16] = (bf16)(of[nt][r] * invr);
  }
}

extern "C" void kernel_launch(void* const* d_in, const int* in_sizes, int n_in,
                              void* d_out, int out_size, void* d_ws, size_t ws_size,
                              hipStream_t stream) {
  const float* iQ = (const float*)d_in[0];
  const int* mask = (const int*)d_in[1];
  const float* Wa = (const float*)d_in[2];
  const float* Wo = (const float*)d_in[3];
  float* out      = (float*)d_out;   // 8.4M fp32 = 32 MB

  // d_out doubles as scratch until the final GEMM overwrites all of it:
  bf16* iQb       = (bf16*)d_out;                     // 16 MB
  bf16* Wab       = iQb + QKV_ELEMS;                  // 6 MB
  unsigned* mbits = (unsigned*)(Wab + 3145728);       // 2 MB
  // Workspace (50 MB): Q/O share a buffer; Wob read by the final GEMM.
  bf16* Qw  = (bf16*)d_ws;        // 16 MB (Q, then O)
  bf16* Kw  = Qw + QKV_ELEMS;     // 16 MB
  bf16* Vtw = Kw + QKV_ELEMS;     // 16 MB
  bf16* Wob = Vtw + QKV_ELEMS;    // 2 MB

  f2b<<<dim3(8388608 / 2048), 256, 0, stream>>>(iQ, iQb);
  f2b<<<dim3(3145728 / 2048), 256, 0, stream>>>(Wa, Wab);
  f2b<<<dim3(1048576 / 2048), 256, 0, stream>>>(Wo, Wob);
  mask_pack<<<dim3((Bc * Sc * Sc / 32) / 256), 256, 0, stream>>>(mask, mbits);
  gemm_bt<0><<<dim3(24, 64), 256, 0, stream>>>(iQb, Wab, Qw, Kw, Vtw, nullptr, 1024, 3072);
  attn<<<dim3(Bc * Hc * 16), 512, 0, stream>>>(Qw, Kw, Vtw, mbits, Qw);
  gemm_bt<1><<<dim3(8, 64), 256, 0, stream>>>(Qw, Wob, nullptr, nullptr, nullptr, out, 1024, 1024);
}

// Round 3
// 374.255 us; speedup vs baseline: 1.0698x; 1.0047x over previous
//
#include <hip/hip_runtime.h>
#include <hip/hip_bf16.h>

// All external tensors are FLOAT32; bf16 is used only internally for MFMA.
typedef __bf16 bf16;
typedef __bf16 bfrag __attribute__((ext_vector_type(8)));   // 8 bf16 = 4 VGPRs (MFMA A/B)
typedef __bf16 bf16x2 __attribute__((ext_vector_type(2)));  // cvt_pk pair
typedef float f32x4 __attribute__((ext_vector_type(4)));    // 16x16 MFMA C/D
typedef float f32x16 __attribute__((ext_vector_type(16)));  // 32x32 MFMA C/D
typedef unsigned u32x2 __attribute__((ext_vector_type(2))); // permlane32_swap result

constexpr int Bc = 4, Sc = 2048, Hc = 16, ADc = 64, HIDc = 1024;
constexpr size_t QKV_ELEMS = (size_t)Bc * Hc * Sc * ADc;    // 8388608 (16 MB bf16)

__device__ __forceinline__ void gload_lds16(const void* g, void* lds) {
  __builtin_amdgcn_global_load_lds(
      (const __attribute__((address_space(1))) unsigned int*)g,
      (__attribute__((address_space(3))) unsigned int*)lds, 16, 0, 0);
}

__device__ __forceinline__ bfrag ldb(const bf16* p) {
  return *(const bfrag*)p;
}

// pack two f32 -> one dword of 2 bf16 (compiler emits v_cvt_pk_bf16_f32)
__device__ __forceinline__ unsigned pack2(float lo, float hi) {
  union { bf16x2 h; unsigned u; } c;
  c.h = bf16x2{(bf16)lo, (bf16)hi};
  return c.u;
}

// v_permlane32_swap_b32 via the documented gfx950 builtin.
// After: a[l] = l<32 ? a_old[l] : b_old[l-32];  b[l] = l<32 ? a_old[l+32] : b_old[l]
__device__ __forceinline__ void plswap(unsigned& a, unsigned& b) {
  u32x2 r = __builtin_amdgcn_permlane32_swap(a, b, false, false);
  a = r.x;
  b = r.y;
}

__device__ __forceinline__ f32x16 zero16() {
  f32x16 z;
#pragma unroll
  for (int i = 0; i < 16; ++i) z[i] = 0.f;
  return z;
}

// ---------------------------------------------------------------------------
// fp32 -> bf16 conversion, 8 elements/thread.
// ---------------------------------------------------------------------------
__global__ __launch_bounds__(256) void f2b(const float* __restrict__ s,
                                           bf16* __restrict__ d) {
  const size_t i = ((size_t)blockIdx.x * 256 + threadIdx.x) * 8;
  const float4 a = *(const float4*)(s + i);
  const float4 b = *(const float4*)(s + i + 4);
  bfrag o = {(bf16)a.x, (bf16)a.y, (bf16)a.z, (bf16)a.w,
             (bf16)b.x, (bf16)b.y, (bf16)b.z, (bf16)b.w};
  *(bfrag*)(d + i) = o;
}

// ---------------------------------------------------------------------------
// GEMM C = A * B^T  (A:[M][K], Bm:[N][K], bf16 in, fp32 accum)
// MODE 0: A row-major; epilogue scatters bf16 Q(x0.125)/K/Vt(transposed)
// MODE 1: A in head-split layout [b][h][s][64]; fp32 store to Cf[M][Ndim]
// ---------------------------------------------------------------------------
template <int MODE>
__global__ __launch_bounds__(256) void gemm_bt(
    const bf16* __restrict__ A,
    const bf16* __restrict__ Bm,
    bf16* __restrict__ C0,
    bf16* __restrict__ C1,
    bf16* __restrict__ C2,
    float* __restrict__ Cf,
    int Kdim, int Ndim)
{
  __shared__ __align__(16) bf16 As[128 * 32];
  __shared__ __align__(16) bf16 Bs[128 * 32];

  const int tid  = threadIdx.x;
  const int wave = tid >> 6;
  const int lane = tid & 63;
  const int n16  = lane & 15;
  const int quad = lane >> 4;
  const int wm   = wave & 1;
  const int wn   = wave >> 1;
  const int m0   = blockIdx.y * 128;
  const int n0   = blockIdx.x * 128;

  const f32x4 fzero = {0.f, 0.f, 0.f, 0.f};
  f32x4 acc[4][4];
#pragma unroll
  for (int i = 0; i < 4; ++i)
#pragma unroll
    for (int j = 0; j < 4; ++j) acc[i][j] = fzero;

  const int lcol = (lane & 3) * 8;  // element offset within the 32-elem LDS row

  for (int k0 = 0; k0 < Kdim; k0 += 32) {
#pragma unroll
    for (int c = 0; c < 2; ++c) {
      const int chunk = wave * 2 + c;          // 0..7, 16 rows each
      const int row   = chunk * 16 + (lane >> 2);
      const bf16* agp;
      if (MODE == 0) {
        agp = A + (size_t)(m0 + row) * Kdim + k0 + lcol;
      } else {
        // A = O in head-split layout [b][h][s][64]; head h = k0>>6.
        const int gs = m0 + row;               // global row (b*2048 + s)
        const int h  = k0 >> 6;
        agp = A + (((size_t)(gs >> 11) * Hc + h) * Sc + (gs & 2047)) * ADc
                + (k0 & 63) + lcol;
      }
      gload_lds16(agp, (char*)As + chunk * 1024);
      gload_lds16(Bm + (size_t)(n0 + row) * Kdim + k0 + lcol,
                  (char*)Bs + chunk * 1024);
    }
    __syncthreads();

    bfrag af[4], bf[4];
#pragma unroll
    for (int i = 0; i < 4; ++i)
      af[i] = ldb(As + (wm * 64 + i * 16 + n16) * 32 + quad * 8);
#pragma unroll
    for (int j = 0; j < 4; ++j)
      bf[j] = ldb(Bs + (wn * 64 + j * 16 + n16) * 32 + quad * 8);
#pragma unroll
    for (int i = 0; i < 4; ++i)
#pragma unroll
      for (int j = 0; j < 4; ++j)
        acc[i][j] = __builtin_amdgcn_mfma_f32_16x16x32_bf16(af[i], bf[j], acc[i][j], 0, 0, 0);
    __syncthreads();
  }

#pragma unroll
  for (int i = 0; i < 4; ++i) {
    const int grow = m0 + wm * 64 + i * 16 + quad * 4;
#pragma unroll
    for (int j = 0; j < 4; ++j) {
      const int col_local = wn * 64 + j * 16 + n16;
#pragma unroll
      for (int r = 0; r < 4; ++r) {
        const int row = grow + r;
        const float v = acc[i][j][r];
        if (MODE == 1) {
          Cf[(size_t)row * Ndim + n0 + col_local] = v;   // fp32 final output
        } else {
          const int seg = n0 >> 10;               // 0=Q 1=K 2=V (uniform per block)
          const int hid = (n0 & 1023) + col_local;
          const int h = hid >> 6, a = hid & 63;
          const int bi = row >> 11, s = row & 2047;
          if (seg == 0)       // Q pre-scaled by 1/sqrt(64) (power of 2: exact)
            C0[(((size_t)bi * Hc + h) * Sc + s) * ADc + a] = (bf16)(v * 0.125f);
          else if (seg == 1)
            C1[(((size_t)bi * Hc + h) * Sc + s) * ADc + a] = (bf16)v;
          else                // V stored transposed: Vt[bh][a][s]
            C2[(((size_t)bi * Hc + h) * ADc + a) * Sc + s] = (bf16)v;
        }
      }
    }
  }
}

// ---------------------------------------------------------------------------
// Pack int32 mask -> 1 bit per element.
// ---------------------------------------------------------------------------
__global__ __launch_bounds__(256) void mask_pack(const int* __restrict__ mask,
                                                 unsigned* __restrict__ bits) {
  const int w = blockIdx.x * 256 + threadIdx.x;
  const int4* p = (const int4*)(mask + (size_t)w * 32);
  unsigned out = 0;
#pragma unroll
  for (int i = 0; i < 8; ++i) {
    int4 m = p[i];
    out |= (unsigned)(m.x != 0) << (i * 4);
    out |= (unsigned)(m.y != 0) << (i * 4 + 1);
    out |= (unsigned)(m.z != 0) << (i * 4 + 2);
    out |= (unsigned)(m.w != 0) << (i * 4 + 3);
  }
  bits[w] = out;
}

// ---------------------------------------------------------------------------
// Flash attention, flat softmax (round-10: 32x32 MFMA, zero-LDS P; same as
// round-9 but permlane32_swap via builtin instead of inline asm).
// 512 threads = 8 waves; each wave owns 32 queries (block = 256 q of one bh).
// Per 64-key tile, K (64x64,[key][dim]) and V^T (64x64,[dim][key]) are staged
// once into XOR-swizzled LDS (16B granule g ^= row&7 -> all frag reads and
// staging writes bank-conflict-free) and shared by all 8 waves. Swapped QK^T
// via 32x32x16 MFMA: S^T = mfma(K, Q) puts P[query=lane&31][16 keys] in regs
// (C-layout: key=(reg&3)+8*(reg>>2)+4*(lane>>5)). The PV A-fragment is then
// assembled ENTIRELY IN REGISTERS: D[m]=cvt_pk(p[2m],p[2m+1]);
// (w0,w2)=permlane32_swap(D[4a],D[4a+2]); (w1,w3)=swap(D[4a+1],D[4a+3])
// -- no P LDS round-trip at all. LDS per wave-tile: 16 ds_read_b128
// (vs 18 b128 + 4 b64 per 16 queries before): ~2.4x less LDS issue per query,
// which was the measured bottleneck (LDS-unit cycles ~= kernel duration).
// Denominator: one lane-local scalar (query lane&31), shfl_xor(32) at end.
// 2-barrier loop with register prefetch of the next tile unchanged.
// ---------------------------------------------------------------------------
__global__ __launch_bounds__(512, 4) void attn(
    const bf16* __restrict__ Qw,
    const bf16* __restrict__ Kw,
    const bf16* __restrict__ Vtw,
    const unsigned* __restrict__ mbits,
    bf16* __restrict__ Ow)   // == Qw (aliased)
{
  __shared__ __align__(16) bf16 Ks[64 * 64];        // [key][dim], XOR-swizzled
  __shared__ __align__(16) bf16 Vs[64 * 64];        // [dim][key], XOR-swizzled

  const int tid  = threadIdx.x;
  const int wave = tid >> 6, lane = tid & 63;
  const int l31  = lane & 31, hi = lane >> 5;
  const int sw   = lane & 7;                        // xor-swizzle key (row&7)
  const int bh   = blockIdx.x >> 3, qb = blockIdx.x & 7;
  const int b    = bh >> 4;
  const int q0w  = qb * 256 + wave * 32;

  // staging coords: thread t -> row t/8, 8-elem chunk (t%8)*8; swizzled dest
  const int srow = tid >> 3;
  const int scol = (tid & 7) * 8;
  const bf16* gK = Kw  + ((size_t)bh * Sc + srow) * ADc + scol;  // +k0*ADc per tile
  const bf16* gV = Vtw + ((size_t)bh * ADc + srow) * Sc + scol;  // +k0 per tile
  bf16* lK = Ks + srow * 64 + (scol ^ ((srow & 7) * 8));
  bf16* lV = Vs + srow * 64 + (scol ^ ((srow & 7) * 8));

  // Q B-frags, resident (pre-scaled by 0.125): row = query q0w+l31,
  // MFMA k = 8*hi + j  ->  element 16*ks + 8*hi + j
  const bf16* qrow = Qw + ((size_t)bh * Sc + q0w + l31) * ADc + hi * 8;
  bfrag qf[4];
#pragma unroll
  for (int ks = 0; ks < 4; ++ks) qf[ks] = ldb(qrow + ks * 16);

  f32x16 of0 = zero16();    // O[query][dim 0..31]
  f32x16 of1 = zero16();    // O[query][dim 32..63]
  float li = 0.f;           // denominator for query l31 (partial: this hi half)

  // one mask row per lane: its query q0w+l31; 64 key-bits per tile = uint2
  const unsigned* mq = mbits + ((size_t)b * Sc + q0w + l31) * (Sc / 32);

  // stage tile 0
  {
    const bfrag k0r = ldb(gK);
    const bfrag v0r = ldb(gV);
    *(bfrag*)lK = k0r;
    *(bfrag*)lV = v0r;
  }
  __syncthreads();

  for (int kt = 0; kt < Sc / 64; ++kt) {
    // prefetch tile kt+1 into regs (wraps on last iter: harmless)
    const int kn0 = ((kt + 1) & 31) * 64;
    const bfrag kpre = ldb(gK + (size_t)kn0 * ADc);
    const bfrag vpre = ldb(gV + kn0);

    // mask bits early (latency overlapped with QK^T)
    const uint2 mwv = *(const uint2*)(mq + kt * 2);

#pragma unroll
    for (int nt = 0; nt < 2; ++nt) {
      // S^T subtile: D[key 32nt+..][query], key = (r&3)+8*(r>>2)+4*hi
      f32x16 sf = zero16();
#pragma unroll
      for (int ks = 0; ks < 4; ++ks) {
        const bfrag kf = ldb(Ks + (nt * 32 + l31) * 64 + (((2 * ks + hi) ^ sw) * 8));
        sf = __builtin_amdgcn_mfma_f32_32x32x16_bf16(kf, qf[ks], sf, 0, 0, 0);
      }

      // softmax: exp, mask (bit (r&3)+8*(r>>2) after pre-shift by 4*hi),
      // accumulate denominator, pack pairs to bf16 dwords
      const unsigned w = (nt ? mwv.y : mwv.x) >> (hi * 4);
      unsigned D[8];
#pragma unroll
      for (int m = 0; m < 8; ++m) {
        const int r0 = 2 * m, r1 = r0 + 1;
        float p0 = __expf(sf[r0]);
        float p1 = __expf(sf[r1]);
        if ((w >> ((r0 & 3) + 8 * (r0 >> 2))) & 1u) p0 = 0.f;
        if ((w >> ((r1 & 3) + 8 * (r1 >> 2))) & 1u) p1 = 0.f;
        li += p0 + p1;
        D[m] = pack2(p0, p1);
      }

      // P A-frags via permlane32_swap (keys 32nt+16a+8hi+j at elem j), then PV
#pragma unroll
      for (int a = 0; a < 2; ++a) {
        unsigned w0 = D[4 * a + 0], w2 = D[4 * a + 2];
        plswap(w0, w2);
        unsigned w1 = D[4 * a + 1], w3 = D[4 * a + 3];
        plswap(w1, w3);
        union { unsigned u[4]; bfrag f; } pu;
        pu.u[0] = w0; pu.u[1] = w1; pu.u[2] = w2; pu.u[3] = w3;
        const int vg = ((4 * nt + 2 * a + hi) ^ sw) * 8;
        const bfrag vf0 = ldb(Vs + l31 * 64 + vg);
        of0 = __builtin_amdgcn_mfma_f32_32x32x16_bf16(pu.f, vf0, of0, 0, 0, 0);
        const bfrag vf1 = ldb(Vs + (32 + l31) * 64 + vg);
        of1 = __builtin_amdgcn_mfma_f32_32x32x16_bf16(pu.f, vf1, of1, 0, 0, 0);
      }
    }

    // swap in the prefetched tile
    __syncthreads();
    *(bfrag*)lK = kpre;
    *(bfrag*)lV = vpre;
    __syncthreads();
  }

  // epilogue: denominator = li(hi=0) + li(hi=1); per-reg query normalization
  const float s = li + __shfl_xor(li, 32);
  const float inv = 1.f / s;
#pragma unroll
  for (int r = 0; r < 16; ++r) {
    const int query = (r & 3) + 8 * (r >> 2) + 4 * hi;
    const float invr = __shfl(inv, query);      // lane `query` holds its denom
    bf16* orow = Ow + ((size_t)bh * Sc + q0w + query) * ADc + l31;
    orow[0]  = (bf16)(of0[r] * invr);
    orow[32] = (bf16)(of1[r] * invr);
  }
}

extern "C" void kernel_launch(void* const* d_in, const int* in_sizes, int n_in,
                              void* d_out, int out_size, void* d_ws, size_t ws_size,
                              hipStream_t stream) {
  const float* iQ = (const float*)d_in[0];
  const int* mask = (const int*)d_in[1];
  const float* Wa = (const float*)d_in[2];
  const float* Wo = (const float*)d_in[3];
  float* out      = (float*)d_out;   // 8.4M fp32 = 32 MB

  // d_out doubles as scratch until the final GEMM overwrites all of it:
  bf16* iQb       = (bf16*)d_out;                     // 16 MB
  bf16* Wab       = iQb + QKV_ELEMS;                  // 6 MB
  unsigned* mbits = (unsigned*)(Wab + 3145728);       // 2 MB
  // Workspace (50 MB): Q/O share a buffer; Wob read by the final GEMM.
  bf16* Qw  = (bf16*)d_ws;        // 16 MB (Q, then O)
  bf16* Kw  = Qw + QKV_ELEMS;     // 16 MB
  bf16* Vtw = Kw + QKV_ELEMS;     // 16 MB
  bf16* Wob = Vtw + QKV_ELEMS;    // 2 MB

  f2b<<<dim3(8388608 / 2048), 256, 0, stream>>>(iQ, iQb);
  f2b<<<dim3(3145728 / 2048), 256, 0, stream>>>(Wa, Wab);
  f2b<<<dim3(1048576 / 2048), 256, 0, stream>>>(Wo, Wob);
  mask_pack<<<dim3((Bc * Sc * Sc / 32) / 256), 256, 0, stream>>>(mask, mbits);
  gemm_bt<0><<<dim3(24, 64), 256, 0, stream>>>(iQb, Wab, Qw, Kw, Vtw, nullptr, 1024, 3072);
  attn<<<dim3(Bc * Hc * 8), 512, 0, stream>>>(Qw, Kw, Vtw, mbits, Qw);
  gemm_bt<1><<<dim3(8, 64), 256, 0, stream>>>(Qw, Wob, nullptr, nullptr, nullptr, out, 1024, 1024);
}